// Round 3
// baseline (348.673 us; speedup 1.0000x reference)
//
#include <hip/hip_runtime.h>

typedef unsigned short u16;
typedef unsigned long long u64;
typedef float f32x4 __attribute__((ext_vector_type(4)));
typedef __bf16 bf16x4 __attribute__((ext_vector_type(4)));
typedef __bf16 bf16x8 __attribute__((ext_vector_type(8)));
typedef u16 u16x8 __attribute__((ext_vector_type(8)));

#define QSCALE 0.18033688011112042f   /* 0.125 * log2(e) */

// ---------- helpers ----------
__device__ __forceinline__ u16 f2bf(float f) {
  unsigned int u = __float_as_uint(f);
  u += 0x7fffu + ((u >> 16) & 1u);   // round-to-nearest-even
  return (u16)(u >> 16);
}

// async global->LDS, 16B per lane; HW dest = readfirstlane(l) + lane*16.
__device__ __forceinline__ void async16(const void* g, void* l) {
  __builtin_amdgcn_global_load_lds(
      (__attribute__((address_space(1))) void*)g,
      (__attribute__((address_space(3))) void*)l,
      16, 0, 0);
}

__device__ __forceinline__ f32x4 mfma16(bf16x8 a, bf16x8 b, f32x4 c) {
  return __builtin_amdgcn_mfma_f32_16x16x32_bf16(a, b, c, 0, 0, 0);
}

// ---------- f32 -> bf16 bulk convert (7 tensors) ----------
struct CvtArgs {
  const float* src[7];
  u16* dst[7];
};

__global__ __launch_bounds__(256) void cvt_kernel(CvtArgs a) {
  int z = blockIdx.z;
  int n = (z < 3) ? 4194304 : 1048576;
  int base = (blockIdx.x * 256 + threadIdx.x) * 8;
  if (base >= n) return;
  const float* s = a.src[z] + base;
  f32x4 x0 = *(const f32x4*)s;
  f32x4 x1 = *(const f32x4*)(s + 4);
  u16x8 pk;
  pk[0]=f2bf(x0[0]); pk[1]=f2bf(x0[1]); pk[2]=f2bf(x0[2]); pk[3]=f2bf(x0[3]);
  pk[4]=f2bf(x1[0]); pk[5]=f2bf(x1[1]); pk[6]=f2bf(x1[2]); pk[7]=f2bf(x1[3]);
  *(u16x8*)(a.dst[z] + base) = pk;
}

// ---------- mask packing: (B,1,S,S) int32 -> (B,S,S/64) uint64 ----------
__global__ __launch_bounds__(256) void pack_mask_kernel(
    const int* __restrict__ mask, u64* __restrict__ pm) {
  int idx = blockIdx.x * 256 + threadIdx.x;
  const int4* src = (const int4*)(mask + (size_t)idx * 64);
  u64 bits = 0ull;
#pragma unroll
  for (int j = 0; j < 16; ++j) {
    int4 v = src[j];
    if (v.x) bits |= 1ull << (4 * j + 0);
    if (v.y) bits |= 1ull << (4 * j + 1);
    if (v.z) bits |= 1ull << (4 * j + 2);
    if (v.w) bits |= 1ull << (4 * j + 3);
  }
  pm[idx] = bits;
}

// ---------- GEMM (m97 structure) ----------
// mode 0: out (B,H,S,Dh)  mode 1: out (B,H,Dh,S)  mode 2: MxN f32
__device__ __forceinline__ void gemm_body(const u16* __restrict__ A,
                                          const u16* __restrict__ W,
                                          const float* __restrict__ bias,
                                          void* __restrict__ outraw, int mode,
                                          float oscale) {
  alignas(16) __shared__ u16 lA[128 * 32];
  alignas(16) __shared__ u16 lB[128 * 32];
  const int tid = threadIdx.x;
  const int lane = tid & 63, wv = tid >> 6;
  const int wm = wv >> 1, wn = wv & 1;
  const int m0 = blockIdx.y * 128, n0 = blockIdx.x * 128;
  const int l15 = lane & 15, quad = lane >> 4;
  const int srow = lane >> 2;
  const int scol = (lane & 3) * 8;

  f32x4 acc[4][4] = {};

  for (int k0 = 0; k0 < 1024; k0 += 32) {
#pragma unroll
    for (int t = 0; t < 2; ++t) {
      int rb = (wv * 2 + t) * 16;
      async16(A + (size_t)(m0 + rb + srow) * 1024 + k0 + scol, (char*)lA + rb * 64);
      async16(W + (size_t)(n0 + rb + srow) * 1024 + k0 + scol, (char*)lB + rb * 64);
    }
    __syncthreads();
    bf16x8 af[4], bfr[4];
#pragma unroll
    for (int i = 0; i < 4; ++i) {
      af[i]  = *(const bf16x8*)(lA + (wm * 64 + i * 16 + l15) * 32 + quad * 8);
      bfr[i] = *(const bf16x8*)(lB + (wn * 64 + i * 16 + l15) * 32 + quad * 8);
    }
#pragma unroll
    for (int i = 0; i < 4; ++i)
#pragma unroll
      for (int j = 0; j < 4; ++j)
        acc[i][j] = mfma16(af[i], bfr[j], acc[i][j]);
    __syncthreads();
  }

#pragma unroll
  for (int i = 0; i < 4; ++i) {
    int mbase = m0 + wm * 64 + i * 16 + quad * 4;
#pragma unroll
    for (int j = 0; j < 4; ++j) {
      int n = n0 + wn * 64 + j * 16 + l15;
      float bv = bias[n];
#pragma unroll
      for (int r = 0; r < 4; ++r) {
        int m = mbase + r;
        float val = (acc[i][j][r] + bv) * oscale;
        if (mode == 0) {
          int b = m >> 11, s = m & 2047, h = n >> 6, dh = n & 63;
          ((u16*)outraw)[((((size_t)b * 16 + h) * 2048 + s) << 6) + dh] = f2bf(val);
        } else if (mode == 1) {
          int b = m >> 11, s = m & 2047, h = n >> 6, dh = n & 63;
          ((u16*)outraw)[((((size_t)b * 16 + h) * 64 + dh) << 11) + s] = f2bf(val);
        } else {
          ((float*)outraw)[(size_t)m * 1024 + n] = val;
        }
      }
    }
  }
}

__global__ __launch_bounds__(256) void gemm_qkv_kernel(
    const u16* __restrict__ qb, const u16* __restrict__ kb, const u16* __restrict__ vb,
    const u16* __restrict__ Wqb, const float* __restrict__ bq,
    const u16* __restrict__ Wkb, const float* __restrict__ bk,
    const u16* __restrict__ Wvb, const float* __restrict__ bv,
    u16* __restrict__ qp, u16* __restrict__ kp, u16* __restrict__ vt) {
  if (blockIdx.z == 0)      gemm_body(qb, Wqb, bq, qp, 0, QSCALE);
  else if (blockIdx.z == 1) gemm_body(kb, Wkb, bk, kp, 0, 1.0f);
  else                      gemm_body(vb, Wvb, bv, vt, 1, 1.0f);
}

__global__ __launch_bounds__(256) void gemm_o_kernel(
    const u16* __restrict__ joint, const u16* __restrict__ Wob,
    const float* __restrict__ bo, float* __restrict__ out) {
  gemm_body(joint, Wob, bo, out, 2, 1.0f);
}

// ---------- flash attention, S^T formulation, 32 q-rows per wave ----------
// Barrier-free version: K/V MFMA fragments are loaded DIRECTLY from global
// into registers with per-lane addresses (byte-identical to the old
// staging(swizzled-global)->LDS->fragment-read composition), so there is no
// cooperative LDS staging and no __syncthreads at all. Waves are fully
// independent (P roundtrip stays in per-wave LDS, lgkmcnt-ordered) and
// desynchronize naturally, overlapping LDS/VALU/MFMA phases across waves.
// K is prefetched one tile ahead (ping-pong kfA/kfB); V is single-buffered
// and loaded just after its previous use (one-iteration slack). vmcnt waits
// are counted by the compiler (in-order vmem return), never drained.
// Softmax runs in-place on S: chunk (g,nt) of tile kt-1 is retired
// immediately before the S-MFMA of tile kt overwrites those registers.
__global__ __launch_bounds__(256, 2) void attn_kernel(
    const u16* __restrict__ qp, const u16* __restrict__ kp,
    const u16* __restrict__ vt, const u64* __restrict__ pm,
    u16* __restrict__ joint) {
  alignas(16) __shared__ u16 pbuf[4][2][1024];  // per wave x group P^T, 2 KB

  const int tid = threadIdx.x, lane = tid & 63, wv = tid >> 6;
  const int quad = lane >> 4, l15 = lane & 15;
  const int q0 = blockIdx.x * 128;
  const int h = blockIdx.y, b = blockIdx.z;
  const size_t head_off = ((size_t)b * 16 + h) * 2048 * 64;
  const u16* Qh = qp + head_off;   // [2048][64]  (pre-scaled)
  const u16* Kh = kp + head_off;   // [2048][64]
  const u16* Vh = vt + head_off;   // [64][2048]  (dh-major)
  const int qr0 = q0 + wv * 32 + l15;          // group 0 q row; group 1 = +16
  const u64* pmq = pm + ((size_t)b * 2048 + qr0) * 32;   // group1 at +512

  // Q fragments: B-operand, lane holds Q[q][quad*8+j]
  bf16x8 qf[2][2];
#pragma unroll
  for (int g = 0; g < 2; ++g) {
    const u16* qrow = Qh + (size_t)(qr0 + g * 16) * 64 + quad * 8;
    qf[g][0] = *(const bf16x8*)(qrow);
    qf[g][1] = *(const bf16x8*)(qrow + 32);
  }

  // per-lane fragment bases:
  // K frag [2*nt+half]: K[kt*64 + nt*16 + l15][half*32 + quad*8 ..+8]
  // V frag [2*nt+ks]:  V^T[nt*16 + l15][kt*64 + ks*32 + quad*8 ..+8]
  const u16* kbase = Kh + (size_t)l15 * 64 + quad * 8;
  const u16* vbase = Vh + (size_t)l15 * 2048 + quad * 8;

  f32x4 O[2][4] = {};              // O^T per group: dh = nt*16+quad*4+r, q = l15
  f32x4 lacc[2] = {};              // vectored l partials (chain depth 4)
  const f32x4 fz = {};

  f32x4 S[2][4];                   // in-place score/softmax registers
  bf16x8 kfA[8], kfB[8];           // K fragment ping-pong (prefetch 1 tile)
  bf16x8 vf[8];                    // V fragments, single-buffered
  u64 wP0, wP1, wC0, wC1;          // mask words (prev / current)

// softmax chunk for one (g,nt) of the PREVIOUS tile: exp2 + mask + l acc +
// bf16 pack + P^T LDS write. Reads+writes S in place; the S-MFMA of the
// current tile overwrites these registers afterwards (program order).
#define SM_CHUNK(WLO, WHI, g, nt)                                              \
  do {                                                                         \
    unsigned int hw_ = ((nt) < 2) ? (WLO) : (WHI);                             \
    unsigned int nib_ = hw_ >> (((nt) & 1) * 16 + quad * 4);                   \
    _Pragma("unroll") for (int r_ = 0; r_ < 4; ++r_) {                         \
      float pe_ = __builtin_amdgcn_exp2f(S[g][nt][r_]);                        \
      S[g][nt][r_] = ((nib_ >> r_) & 1u) ? pe_ : 0.f;                          \
    }                                                                          \
    lacc[g] += S[g][nt];                                                       \
    bf16x4 pv_ = __builtin_convertvector(S[g][nt], bf16x4);                    \
    int t4_ = 4 * (nt) + quad;                                                 \
    int ks_ = t4_ >> 3, qd_ = (t4_ & 7) >> 1;                                  \
    u16* pw_ = pbuf[wv][g] + ks_ * 512 + qd_ * 128 + l15 * 8 + (t4_ & 1) * 4;  \
    *(u64*)pw_ = *(const u64*)&pv_;                                            \
  } while (0)

// one pipeline step at tile kt (kt>=1):
//  a. issue K(kt+1) global loads into KFN
//  b. load mask words for kt (consumed next step)
//  c. per nt: softmax(tile kt-1 chunk) then S-MFMA(tile kt chunk) in place
//  d. P fragment reads + PV(kt-1) with vf = V(kt-1)
//  e. issue V(kt) global loads into vf (consumed next step / retire)
#define ATTN_STEP(KFC, KFN, KT)                                                \
  do {                                                                         \
    const int kt_ = (KT);                                                      \
    if (kt_ != 31) {                                                           \
      const u16* kn_ = kbase + (size_t)(kt_ + 1) * 4096;                       \
      _Pragma("unroll") for (int nt = 0; nt < 4; ++nt) {                       \
        KFN[2 * nt]     = *(const bf16x8*)(kn_ + nt * 1024);                   \
        KFN[2 * nt + 1] = *(const bf16x8*)(kn_ + nt * 1024 + 32);              \
      }                                                                        \
    }                                                                          \
    wC0 = pmq[kt_]; wC1 = pmq[kt_ + 512];                                      \
    unsigned int plo0_ = (unsigned int)wP0, phi0_ = (unsigned int)(wP0 >> 32); \
    unsigned int plo1_ = (unsigned int)wP1, phi1_ = (unsigned int)(wP1 >> 32); \
    _Pragma("unroll") for (int nt = 0; nt < 4; ++nt) {                         \
      SM_CHUNK(plo0_, phi0_, 0, nt);                                           \
      SM_CHUNK(plo1_, phi1_, 1, nt);                                           \
      f32x4 z0_ = mfma16(KFC[2 * nt], qf[0][0], fz);                           \
      S[0][nt] = mfma16(KFC[2 * nt + 1], qf[0][1], z0_);                       \
      f32x4 z1_ = mfma16(KFC[2 * nt], qf[1][0], fz);                           \
      S[1][nt] = mfma16(KFC[2 * nt + 1], qf[1][1], z1_);                       \
    }                                                                          \
    asm volatile("s_waitcnt lgkmcnt(0)" ::: "memory");                         \
    _Pragma("unroll") for (int ks = 0; ks < 2; ++ks) {                         \
      bf16x8 pf0_ = *(const bf16x8*)(pbuf[wv][0] + ks * 512 + lane * 8);       \
      bf16x8 pf1_ = *(const bf16x8*)(pbuf[wv][1] + ks * 512 + lane * 8);       \
      _Pragma("unroll") for (int nt = 0; nt < 4; ++nt) {                       \
        O[0][nt] = mfma16(vf[2 * nt + ks], pf0_, O[0][nt]);                    \
        O[1][nt] = mfma16(vf[2 * nt + ks], pf1_, O[1][nt]);                    \
      }                                                                        \
    }                                                                          \
    {                                                                          \
      const u16* vn_ = vbase + (size_t)kt_ * 64;                               \
      _Pragma("unroll") for (int nt = 0; nt < 4; ++nt) {                       \
        vf[2 * nt]     = *(const bf16x8*)(vn_ + nt * 32768);                   \
        vf[2 * nt + 1] = *(const bf16x8*)(vn_ + nt * 32768 + 32);              \
      }                                                                        \
    }                                                                          \
    wP0 = wC0; wP1 = wC1;                                                      \
  } while (0)

  // ---- prologue: K(0) -> kfA, S(0), then K(1) -> kfB and V(0) -> vf ----
#pragma unroll
  for (int nt = 0; nt < 4; ++nt) {
    kfA[2 * nt]     = *(const bf16x8*)(kbase + nt * 1024);
    kfA[2 * nt + 1] = *(const bf16x8*)(kbase + nt * 1024 + 32);
  }
  wP0 = pmq[0]; wP1 = pmq[512];
#pragma unroll
  for (int nt = 0; nt < 4; ++nt) {
    f32x4 z0 = mfma16(kfA[2 * nt], qf[0][0], fz);
    S[0][nt] = mfma16(kfA[2 * nt + 1], qf[0][1], z0);
    f32x4 z1 = mfma16(kfA[2 * nt], qf[1][0], fz);
    S[1][nt] = mfma16(kfA[2 * nt + 1], qf[1][1], z1);
  }
#pragma unroll
  for (int nt = 0; nt < 4; ++nt) {
    kfB[2 * nt]     = *(const bf16x8*)(kbase + 4096 + nt * 1024);
    kfB[2 * nt + 1] = *(const bf16x8*)(kbase + 4096 + nt * 1024 + 32);
  }
#pragma unroll
  for (int nt = 0; nt < 4; ++nt) {
    vf[2 * nt]     = *(const bf16x8*)(vbase + nt * 32768);
    vf[2 * nt + 1] = *(const bf16x8*)(vbase + nt * 32768 + 32);
  }

  // ---- main pipeline: tiles 1..31 (retiring softmax/PV of 0..30) ----
  for (int it = 0; it < 15; ++it) {
    ATTN_STEP(kfB, kfA, 2 * it + 1);
    ATTN_STEP(kfA, kfB, 2 * it + 2);
  }
  ATTN_STEP(kfB, kfA, 31);

  // ---- retire tile 31: softmax + PV (vf = V(31), wP = masks(31)) ----
  {
    unsigned int plo0_ = (unsigned int)wP0, phi0_ = (unsigned int)(wP0 >> 32);
    unsigned int plo1_ = (unsigned int)wP1, phi1_ = (unsigned int)(wP1 >> 32);
#pragma unroll
    for (int nt = 0; nt < 4; ++nt) {
      SM_CHUNK(plo0_, phi0_, 0, nt);
      SM_CHUNK(plo1_, phi1_, 1, nt);
    }
    asm volatile("s_waitcnt lgkmcnt(0)" ::: "memory");
#pragma unroll
    for (int ks = 0; ks < 2; ++ks) {
      bf16x8 pf0_ = *(const bf16x8*)(pbuf[wv][0] + ks * 512 + lane * 8);
      bf16x8 pf1_ = *(const bf16x8*)(pbuf[wv][1] + ks * 512 + lane * 8);
#pragma unroll
      for (int nt = 0; nt < 4; ++nt) {
        O[0][nt] = mfma16(vf[2 * nt + ks], pf0_, O[0][nt]);
        O[1][nt] = mfma16(vf[2 * nt + ks], pf1_, O[1][nt]);
      }
    }
  }

#undef ATTN_STEP
#undef SM_CHUNK

  // ---- epilogue ----
#pragma unroll
  for (int g = 0; g < 2; ++g) {
    float l = (lacc[g][0] + lacc[g][1]) + (lacc[g][2] + lacc[g][3]);
    l += __shfl_xor(l, 16, 64);
    l += __shfl_xor(l, 32, 64);
    float inv = 1.0f / l;
    size_t row_off = ((size_t)b * 2048 + qr0 + g * 16) * 1024 + h * 64;
#pragma unroll
    for (int nt = 0; nt < 4; ++nt) {
      f32x4 ov = O[g][nt] * inv;
      bf16x4 obv = __builtin_convertvector(ov, bf16x4);
      *(u64*)(joint + row_off + nt * 16 + quad * 4) = *(const u64*)&obv;
    }
  }
}

// ---------- launch ----------
extern "C" void kernel_launch(void* const* d_in, const int* in_sizes, int n_in,
                              void* d_out, int out_size, void* d_ws, size_t ws_size,
                              hipStream_t stream) {
  const float* q  = (const float*)d_in[0];
  const float* k  = (const float*)d_in[1];
  const float* v  = (const float*)d_in[2];
  const int* mask = (const int*)d_in[3];
  const float* Wq = (const float*)d_in[4];
  const float* bq = (const float*)d_in[5];
  const float* Wk = (const float*)d_in[6];
  const float* bk = (const float*)d_in[7];
  const float* Wv = (const float*)d_in[8];
  const float* bv = (const float*)d_in[9];
  const float* Wo = (const float*)d_in[10];
  const float* bo = (const float*)d_in[11];
  float* out = (float*)d_out;

  u16* w = (u16*)d_ws;
  u16* qp    = w;                         // (B,H,S,Dh)
  u16* kp    = w + 4194304;               // (B,H,S,Dh)
  u16* vt    = w + 8388608;               // (B,H,Dh,S)
  u16* qb    = w + 12582912;              // bf16 q; joint aliases after attn
  u16* kb    = w + 16777216;
  u16* vb    = w + 20971520;
  u16* Wqb   = w + 25165824;
  u16* Wkb   = w + 26214400;
  u16* Wvb   = w + 27262976;
  u16* Wob   = w + 28311552;
  u64* pm    = (u64*)(w + 29360128);
  u16* joint = qb;

  CvtArgs ca;
  ca.src[0] = q;  ca.dst[0] = qb;
  ca.src[1] = k;  ca.dst[1] = kb;
  ca.src[2] = v;  ca.dst[2] = vb;
  ca.src[3] = Wq; ca.dst[3] = Wqb;
  ca.src[4] = Wk; ca.dst[4] = Wkb;
  ca.src[5] = Wv; ca.dst[5] = Wvb;
  ca.src[6] = Wo; ca.dst[6] = Wob;

  pack_mask_kernel<<<dim3(512), dim3(256), 0, stream>>>(mask, pm);
  cvt_kernel<<<dim3(2048, 1, 7), dim3(256), 0, stream>>>(ca);
  gemm_qkv_kernel<<<dim3(8, 32, 3), dim3(256), 0, stream>>>(
      qb, kb, vb, Wqb, bq, Wkb, bk, Wvb, bv, qp, kp, vt);
  attn_kernel<<<dim3(16, 16, 2), dim3(256), 0, stream>>>(qp, kp, vt, pm, joint);
  gemm_o_kernel<<<dim3(8, 32, 1), dim3(256), 0, stream>>>(joint, Wob, bo, out);
}

// Round 4
// 300.445 us; speedup vs baseline: 1.1605x; 1.1605x over previous
//
#include <hip/hip_runtime.h>

typedef unsigned short u16;
typedef unsigned long long u64;
typedef float f32x4 __attribute__((ext_vector_type(4)));
typedef __bf16 bf16x4 __attribute__((ext_vector_type(4)));
typedef __bf16 bf16x8 __attribute__((ext_vector_type(8)));
typedef u16 u16x8 __attribute__((ext_vector_type(8)));

#define QSCALE 0.18033688011112042f   /* 0.125 * log2(e) */

// ---------- helpers ----------
__device__ __forceinline__ u16 f2bf(float f) {
  unsigned int u = __float_as_uint(f);
  u += 0x7fffu + ((u >> 16) & 1u);   // round-to-nearest-even
  return (u16)(u >> 16);
}

// async global->LDS, 16B per lane; HW dest = readfirstlane(l) + lane*16.
__device__ __forceinline__ void async16(const void* g, void* l) {
  __builtin_amdgcn_global_load_lds(
      (__attribute__((address_space(1))) void*)g,
      (__attribute__((address_space(3))) void*)l,
      16, 0, 0);
}

__device__ __forceinline__ f32x4 mfma16(bf16x8 a, bf16x8 b, f32x4 c) {
  return __builtin_amdgcn_mfma_f32_16x16x32_bf16(a, b, c, 0, 0, 0);
}

// ---------- f32 -> bf16 bulk convert (7 tensors) ----------
struct CvtArgs {
  const float* src[7];
  u16* dst[7];
};

__global__ __launch_bounds__(256) void cvt_kernel(CvtArgs a) {
  int z = blockIdx.z;
  int n = (z < 3) ? 4194304 : 1048576;
  int base = (blockIdx.x * 256 + threadIdx.x) * 8;
  if (base >= n) return;
  const float* s = a.src[z] + base;
  f32x4 x0 = *(const f32x4*)s;
  f32x4 x1 = *(const f32x4*)(s + 4);
  u16x8 pk;
  pk[0]=f2bf(x0[0]); pk[1]=f2bf(x0[1]); pk[2]=f2bf(x0[2]); pk[3]=f2bf(x0[3]);
  pk[4]=f2bf(x1[0]); pk[5]=f2bf(x1[1]); pk[6]=f2bf(x1[2]); pk[7]=f2bf(x1[3]);
  *(u16x8*)(a.dst[z] + base) = pk;
}

// ---------- mask packing: (B,1,S,S) int32 -> (B,S,S/64) uint64 ----------
__global__ __launch_bounds__(256) void pack_mask_kernel(
    const int* __restrict__ mask, u64* __restrict__ pm) {
  int idx = blockIdx.x * 256 + threadIdx.x;
  const int4* src = (const int4*)(mask + (size_t)idx * 64);
  u64 bits = 0ull;
#pragma unroll
  for (int j = 0; j < 16; ++j) {
    int4 v = src[j];
    if (v.x) bits |= 1ull << (4 * j + 0);
    if (v.y) bits |= 1ull << (4 * j + 1);
    if (v.z) bits |= 1ull << (4 * j + 2);
    if (v.w) bits |= 1ull << (4 * j + 3);
  }
  pm[idx] = bits;
}

// ---------- GEMM (m97 structure) ----------
// mode 0: out (B,H,S,Dh)  mode 1: out (B,H,Dh,S)  mode 2: MxN f32
__device__ __forceinline__ void gemm_body(const u16* __restrict__ A,
                                          const u16* __restrict__ W,
                                          const float* __restrict__ bias,
                                          void* __restrict__ outraw, int mode,
                                          float oscale) {
  alignas(16) __shared__ u16 lA[128 * 32];
  alignas(16) __shared__ u16 lB[128 * 32];
  const int tid = threadIdx.x;
  const int lane = tid & 63, wv = tid >> 6;
  const int wm = wv >> 1, wn = wv & 1;
  const int m0 = blockIdx.y * 128, n0 = blockIdx.x * 128;
  const int l15 = lane & 15, quad = lane >> 4;
  const int srow = lane >> 2;
  const int scol = (lane & 3) * 8;

  f32x4 acc[4][4] = {};

  for (int k0 = 0; k0 < 1024; k0 += 32) {
#pragma unroll
    for (int t = 0; t < 2; ++t) {
      int rb = (wv * 2 + t) * 16;
      async16(A + (size_t)(m0 + rb + srow) * 1024 + k0 + scol, (char*)lA + rb * 64);
      async16(W + (size_t)(n0 + rb + srow) * 1024 + k0 + scol, (char*)lB + rb * 64);
    }
    __syncthreads();
    bf16x8 af[4], bfr[4];
#pragma unroll
    for (int i = 0; i < 4; ++i) {
      af[i]  = *(const bf16x8*)(lA + (wm * 64 + i * 16 + l15) * 32 + quad * 8);
      bfr[i] = *(const bf16x8*)(lB + (wn * 64 + i * 16 + l15) * 32 + quad * 8);
    }
#pragma unroll
    for (int i = 0; i < 4; ++i)
#pragma unroll
      for (int j = 0; j < 4; ++j)
        acc[i][j] = mfma16(af[i], bfr[j], acc[i][j]);
    __syncthreads();
  }

#pragma unroll
  for (int i = 0; i < 4; ++i) {
    int mbase = m0 + wm * 64 + i * 16 + quad * 4;
#pragma unroll
    for (int j = 0; j < 4; ++j) {
      int n = n0 + wn * 64 + j * 16 + l15;
      float bv = bias[n];
#pragma unroll
      for (int r = 0; r < 4; ++r) {
        int m = mbase + r;
        float val = (acc[i][j][r] + bv) * oscale;
        if (mode == 0) {
          int b = m >> 11, s = m & 2047, h = n >> 6, dh = n & 63;
          ((u16*)outraw)[((((size_t)b * 16 + h) * 2048 + s) << 6) + dh] = f2bf(val);
        } else if (mode == 1) {
          int b = m >> 11, s = m & 2047, h = n >> 6, dh = n & 63;
          ((u16*)outraw)[((((size_t)b * 16 + h) * 64 + dh) << 11) + s] = f2bf(val);
        } else {
          ((float*)outraw)[(size_t)m * 1024 + n] = val;
        }
      }
    }
  }
}

__global__ __launch_bounds__(256) void gemm_qkv_kernel(
    const u16* __restrict__ qb, const u16* __restrict__ kb, const u16* __restrict__ vb,
    const u16* __restrict__ Wqb, const float* __restrict__ bq,
    const u16* __restrict__ Wkb, const float* __restrict__ bk,
    const u16* __restrict__ Wvb, const float* __restrict__ bv,
    u16* __restrict__ qp, u16* __restrict__ kp, u16* __restrict__ vt) {
  if (blockIdx.z == 0)      gemm_body(qb, Wqb, bq, qp, 0, QSCALE);
  else if (blockIdx.z == 1) gemm_body(kb, Wkb, bk, kp, 0, 1.0f);
  else                      gemm_body(vb, Wvb, bv, vt, 1, 1.0f);
}

__global__ __launch_bounds__(256) void gemm_o_kernel(
    const u16* __restrict__ joint, const u16* __restrict__ Wob,
    const float* __restrict__ bo, float* __restrict__ out) {
  gemm_body(joint, Wob, bo, out, 2, 1.0f);
}

// ---------- flash attention, S^T formulation, 16 q-rows per wave ----------
// Occupancy experiment: per-wave q-tile halved (32 -> 16 rows), grid doubled
// to 1024 blocks -> 4 blocks/CU, 4 waves/SIMD, each SIMD's waves drawn from
// INDEPENDENT blocks (separate barrier groups). Rounds 0-2 showed the
// 2-waves/SIMD version serializes its LDS/MFMA/VALU phases (sum of pipe
// busy == wall) and that intra-wave ILP restructures cannot fix it; this
// buys cross-wave overlap with TLP instead. LDS = 16K(K)+16K(V)+8K(P)
// = 40960 B/block -> exactly 4 blocks at the 160 KB pool.
// K/V staging geometry and fragment maps identical to the verified 32q
// kernel; only the q-group dimension is dropped.
__global__ __launch_bounds__(256, 4) void attn_kernel(
    const u16* __restrict__ qp, const u16* __restrict__ kp,
    const u16* __restrict__ vt, const u64* __restrict__ pm,
    u16* __restrict__ joint) {
  alignas(16) __shared__ u16 kbuf[2][4096];     // 2 x 8 KB
  alignas(16) __shared__ u16 vbuf[2][4096];     // 2 x 8 KB
  alignas(16) __shared__ u16 pbuf[4][1024];     // per wave P^T, 2 KB

  const int tid = threadIdx.x, lane = tid & 63, wv = tid >> 6;
  const int quad = lane >> 4, l15 = lane & 15;
  const int q0 = blockIdx.x * 64;
  const int h = blockIdx.y, b = blockIdx.z;
  const size_t head_off = ((size_t)b * 16 + h) * 2048 * 64;
  const u16* Qh = qp + head_off;   // [2048][64]  (pre-scaled)
  const u16* Kh = kp + head_off;   // [2048][64]
  const u16* Vh = vt + head_off;   // [64][2048]  (dh-major)
  const int qr = q0 + wv * 16 + l15;           // this wave's q row
  const u64* pmq = pm + ((size_t)b * 2048 + qr) * 32;

  // Q fragments: B-operand, lane holds Q[qr][quad*8+j]
  bf16x8 qf[2];
  {
    const u16* qrow = Qh + (size_t)qr * 64 + quad * 8;
    qf[0] = *(const bf16x8*)(qrow);
    qf[1] = *(const bf16x8*)(qrow + 32);
  }

  // staging geometry (identical to verified pattern)
  const int sd0 = tid, sd1 = 256 + tid;
  const int snt0 = sd0 >> 7, shalf0 = (sd0 >> 6) & 1, sl60 = sd0 & 63;
  const int snt1 = sd1 >> 7, shalf1 = (sd1 >> 6) & 1, sl61 = sd1 & 63;
  const u16* kg0 = Kh + (size_t)(snt0 * 16 + (sl60 & 15)) * 64 + shalf0 * 32 + (sl60 >> 4) * 8;
  const u16* kg1 = Kh + (size_t)(snt1 * 16 + (sl61 & 15)) * 64 + shalf1 * 32 + (sl61 >> 4) * 8;
  const int vb0 = sd0 >> 6, vb1 = sd1 >> 6;
  const u16* vg0 = Vh + (size_t)((vb0 >> 1) * 16 + (sl60 & 15)) * 2048 + (vb0 & 1) * 32 + (sl60 >> 4) * 8;
  const u16* vg1 = Vh + (size_t)((vb1 >> 1) * 16 + (sl61 & 15)) * 2048 + (vb1 & 1) * 32 + (sl61 >> 4) * 8;

  f32x4 O[4] = {};                 // O^T: dh = nt*16+quad*4+r, q = l15
  f32x4 lacc = {};                 // vectored l partials (chain depth 4)
  const f32x4 fz = {};

  // prologue: stage tile 0
  async16(kg0, (char*)kbuf[0] + sd0 * 16);
  async16(kg1, (char*)kbuf[0] + sd1 * 16);
  async16(vg0, (char*)vbuf[0] + sd0 * 16);
  async16(vg1, (char*)vbuf[0] + sd1 * 16);

  for (int kt = 0; kt < 32; ++kt) {
    __syncthreads();

    // prefetch next tile
    if (kt != 31) {
      const size_t kadv = (size_t)(kt + 1) * 4096;   // 64 rows x 64 elems
      const int vadv = (kt + 1) * 64;                // +64 columns
      char* kd = (char*)kbuf[(kt + 1) & 1];
      char* vd = (char*)vbuf[(kt + 1) & 1];
      async16(kg0 + kadv, kd + sd0 * 16);
      async16(kg1 + kadv, kd + sd1 * 16);
      async16(vg0 + vadv, vd + sd0 * 16);
      async16(vg1 + vadv, vd + sd1 * 16);
    }

    u64 word = pmq[kt];
    const u16* kc = kbuf[kt & 1];
    const u16* vc = vbuf[kt & 1];

    // ---- K fragments ----
    bf16x8 kf[8];
#pragma unroll
    for (int nt = 0; nt < 4; ++nt) {
      kf[2 * nt]     = *(const bf16x8*)(kc + nt * 1024 + lane * 8);
      kf[2 * nt + 1] = *(const bf16x8*)(kc + nt * 1024 + 512 + lane * 8);
    }

    // ---- S^T = K·Q^T ----
    f32x4 S[4];
#pragma unroll
    for (int nt = 0; nt < 4; ++nt) {
      f32x4 z = mfma16(kf[2 * nt], qf[0], fz);
      S[nt] = mfma16(kf[2 * nt + 1], qf[1], z);
    }

    // ---- masked exp2 + vectored l accumulation + P^T pack ----
    {
      unsigned int wlo = (unsigned int)word, whi = (unsigned int)(word >> 32);
#pragma unroll
      for (int nt = 0; nt < 4; ++nt) {
        unsigned int hw = (nt < 2) ? wlo : whi;
        unsigned int nib = hw >> ((nt & 1) * 16 + quad * 4);
#pragma unroll
        for (int r = 0; r < 4; ++r) {
          float pe = __builtin_amdgcn_exp2f(S[nt][r]);
          S[nt][r] = ((nib >> r) & 1u) ? pe : 0.f;
        }
        lacc += S[nt];
        bf16x4 pv = __builtin_convertvector(S[nt], bf16x4);
        int t4 = 4 * nt + quad;
        int ks = t4 >> 3, qd = (t4 & 7) >> 1;
        u16* pw = pbuf[wv] + ks * 512 + qd * 128 + l15 * 8 + (t4 & 1) * 4;
        *(u64*)pw = *(const u64*)&pv;
      }
    }

    // ---- V fragments ----
    bf16x8 vf[8];
#pragma unroll
    for (int nt = 0; nt < 4; ++nt) {
      vf[2 * nt]     = *(const bf16x8*)(vc + (nt * 2) * 512 + lane * 8);
      vf[2 * nt + 1] = *(const bf16x8*)(vc + (nt * 2 + 1) * 512 + lane * 8);
    }
    asm volatile("s_waitcnt lgkmcnt(0)" ::: "memory");  // P writes + vf visible

    // ---- O^T += V^T · P^T ----
#pragma unroll
    for (int ks = 0; ks < 2; ++ks) {
      bf16x8 pf = *(const bf16x8*)(pbuf[wv] + ks * 512 + lane * 8);
#pragma unroll
      for (int nt = 0; nt < 4; ++nt)
        O[nt] = mfma16(vf[2 * nt + ks], pf, O[nt]);
    }
  }

  // ---- epilogue ----
  {
    float l = (lacc[0] + lacc[1]) + (lacc[2] + lacc[3]);
    l += __shfl_xor(l, 16, 64);
    l += __shfl_xor(l, 32, 64);
    float inv = 1.0f / l;
    size_t row_off = ((size_t)b * 2048 + qr) * 1024 + h * 64;
#pragma unroll
    for (int nt = 0; nt < 4; ++nt) {
      f32x4 ov = O[nt] * inv;
      bf16x4 obv = __builtin_convertvector(ov, bf16x4);
      *(u64*)(joint + row_off + nt * 16 + quad * 4) = *(const u64*)&obv;
    }
  }
}

// ---------- launch ----------
extern "C" void kernel_launch(void* const* d_in, const int* in_sizes, int n_in,
                              void* d_out, int out_size, void* d_ws, size_t ws_size,
                              hipStream_t stream) {
  const float* q  = (const float*)d_in[0];
  const float* k  = (const float*)d_in[1];
  const float* v  = (const float*)d_in[2];
  const int* mask = (const int*)d_in[3];
  const float* Wq = (const float*)d_in[4];
  const float* bq = (const float*)d_in[5];
  const float* Wk = (const float*)d_in[6];
  const float* bk = (const float*)d_in[7];
  const float* Wv = (const float*)d_in[8];
  const float* bv = (const float*)d_in[9];
  const float* Wo = (const float*)d_in[10];
  const float* bo = (const float*)d_in[11];
  float* out = (float*)d_out;

  u16* w = (u16*)d_ws;
  u16* qp    = w;                         // (B,H,S,Dh)
  u16* kp    = w + 4194304;               // (B,H,S,Dh)
  u16* vt    = w + 8388608;               // (B,H,Dh,S)
  u16* qb    = w + 12582912;              // bf16 q; joint aliases after attn
  u16* kb    = w + 16777216;
  u16* vb    = w + 20971520;
  u16* Wqb   = w + 25165824;
  u16* Wkb   = w + 26214400;
  u16* Wvb   = w + 27262976;
  u16* Wob   = w + 28311552;
  u64* pm    = (u64*)(w + 29360128);
  u16* joint = qb;

  CvtArgs ca;
  ca.src[0] = q;  ca.dst[0] = qb;
  ca.src[1] = k;  ca.dst[1] = kb;
  ca.src[2] = v;  ca.dst[2] = vb;
  ca.src[3] = Wq; ca.dst[3] = Wqb;
  ca.src[4] = Wk; ca.dst[4] = Wkb;
  ca.src[5] = Wv; ca.dst[5] = Wvb;
  ca.src[6] = Wo; ca.dst[6] = Wob;

  pack_mask_kernel<<<dim3(512), dim3(256), 0, stream>>>(mask, pm);
  cvt_kernel<<<dim3(2048, 1, 7), dim3(256), 0, stream>>>(ca);
  gemm_qkv_kernel<<<dim3(8, 32, 3), dim3(256), 0, stream>>>(
      qb, kb, vb, Wqb, bq, Wkb, bk, Wvb, bv, qp, kp, vt);
  attn_kernel<<<dim3(32, 16, 2), dim3(256), 0, stream>>>(qp, kp, vt, pm, joint);
  gemm_o_kernel<<<dim3(8, 32, 1), dim3(256), 0, stream>>>(joint, Wob, bo, out);
}

// Round 5
// 286.090 us; speedup vs baseline: 1.2188x; 1.0502x over previous
//
#include <hip/hip_runtime.h>

typedef unsigned short u16;
typedef unsigned int u32;
typedef unsigned long long u64;
typedef float f32x4 __attribute__((ext_vector_type(4)));
typedef float f32x16 __attribute__((ext_vector_type(16)));
typedef __bf16 bf16x4 __attribute__((ext_vector_type(4)));
typedef __bf16 bf16x8 __attribute__((ext_vector_type(8)));
typedef u16 u16x8 __attribute__((ext_vector_type(8)));
typedef u32 u32x4 __attribute__((ext_vector_type(4)));

#define QSCALE 0.18033688011112042f   /* 0.125 * log2(e) */

// ---------- helpers ----------
__device__ __forceinline__ u16 f2bf(float f) {
  unsigned int u = __float_as_uint(f);
  u += 0x7fffu + ((u >> 16) & 1u);   // round-to-nearest-even
  return (u16)(u >> 16);
}

// async global->LDS, 16B per lane; HW dest = readfirstlane(l) + lane*16.
__device__ __forceinline__ void async16(const void* g, void* l) {
  __builtin_amdgcn_global_load_lds(
      (__attribute__((address_space(1))) void*)g,
      (__attribute__((address_space(3))) void*)l,
      16, 0, 0);
}

__device__ __forceinline__ f32x4 mfma16(bf16x8 a, bf16x8 b, f32x4 c) {
  return __builtin_amdgcn_mfma_f32_16x16x32_bf16(a, b, c, 0, 0, 0);
}

__device__ __forceinline__ f32x16 mfma32(bf16x8 a, bf16x8 b, f32x16 c) {
  return __builtin_amdgcn_mfma_f32_32x32x16_bf16(a, b, c, 0, 0, 0);
}

// pack two f32 -> dword of 2 bf16 (RNE)
__device__ __forceinline__ u32 cvtpk(float lo, float hi) {
  u32 r;
  asm("v_cvt_pk_bf16_f32 %0, %1, %2" : "=v"(r) : "v"(lo), "v"(hi));
  return r;
}

// a' = {a.lo32lanes, b.lo32lanes}; b' = {a.hi32lanes, b.hi32lanes}
__device__ __forceinline__ void pswap(u32& a, u32& b) {
  asm("v_permlane32_swap_b32 %0, %1" : "+v"(a), "+v"(b));
}

// ---------- f32 -> bf16 bulk convert (7 tensors) ----------
struct CvtArgs {
  const float* src[7];
  u16* dst[7];
};

__global__ __launch_bounds__(256) void cvt_kernel(CvtArgs a) {
  int z = blockIdx.z;
  int n = (z < 3) ? 4194304 : 1048576;
  int base = (blockIdx.x * 256 + threadIdx.x) * 8;
  if (base >= n) return;
  const float* s = a.src[z] + base;
  f32x4 x0 = *(const f32x4*)s;
  f32x4 x1 = *(const f32x4*)(s + 4);
  u16x8 pk;
  pk[0]=f2bf(x0[0]); pk[1]=f2bf(x0[1]); pk[2]=f2bf(x0[2]); pk[3]=f2bf(x0[3]);
  pk[4]=f2bf(x1[0]); pk[5]=f2bf(x1[1]); pk[6]=f2bf(x1[2]); pk[7]=f2bf(x1[3]);
  *(u16x8*)(a.dst[z] + base) = pk;
}

// ---------- mask packing: (B,1,S,S) int32 -> (B,S,S/64) uint64 ----------
__global__ __launch_bounds__(256) void pack_mask_kernel(
    const int* __restrict__ mask, u64* __restrict__ pm) {
  int idx = blockIdx.x * 256 + threadIdx.x;
  const int4* src = (const int4*)(mask + (size_t)idx * 64);
  u64 bits = 0ull;
#pragma unroll
  for (int j = 0; j < 16; ++j) {
    int4 v = src[j];
    if (v.x) bits |= 1ull << (4 * j + 0);
    if (v.y) bits |= 1ull << (4 * j + 1);
    if (v.z) bits |= 1ull << (4 * j + 2);
    if (v.w) bits |= 1ull << (4 * j + 3);
  }
  pm[idx] = bits;
}

// ---------- GEMM (m97 structure) ----------
// mode 0: out (B,H,S,Dh)  mode 1: out (B,H,Dh,S)  mode 2: MxN f32
__device__ __forceinline__ void gemm_body(const u16* __restrict__ A,
                                          const u16* __restrict__ W,
                                          const float* __restrict__ bias,
                                          void* __restrict__ outraw, int mode,
                                          float oscale) {
  alignas(16) __shared__ u16 lA[128 * 32];
  alignas(16) __shared__ u16 lB[128 * 32];
  const int tid = threadIdx.x;
  const int lane = tid & 63, wv = tid >> 6;
  const int wm = wv >> 1, wn = wv & 1;
  const int m0 = blockIdx.y * 128, n0 = blockIdx.x * 128;
  const int l15 = lane & 15, quad = lane >> 4;
  const int srow = lane >> 2;
  const int scol = (lane & 3) * 8;

  f32x4 acc[4][4] = {};

  for (int k0 = 0; k0 < 1024; k0 += 32) {
#pragma unroll
    for (int t = 0; t < 2; ++t) {
      int rb = (wv * 2 + t) * 16;
      async16(A + (size_t)(m0 + rb + srow) * 1024 + k0 + scol, (char*)lA + rb * 64);
      async16(W + (size_t)(n0 + rb + srow) * 1024 + k0 + scol, (char*)lB + rb * 64);
    }
    __syncthreads();
    bf16x8 af[4], bfr[4];
#pragma unroll
    for (int i = 0; i < 4; ++i) {
      af[i]  = *(const bf16x8*)(lA + (wm * 64 + i * 16 + l15) * 32 + quad * 8);
      bfr[i] = *(const bf16x8*)(lB + (wn * 64 + i * 16 + l15) * 32 + quad * 8);
    }
#pragma unroll
    for (int i = 0; i < 4; ++i)
#pragma unroll
      for (int j = 0; j < 4; ++j)
        acc[i][j] = mfma16(af[i], bfr[j], acc[i][j]);
    __syncthreads();
  }

#pragma unroll
  for (int i = 0; i < 4; ++i) {
    int mbase = m0 + wm * 64 + i * 16 + quad * 4;
#pragma unroll
    for (int j = 0; j < 4; ++j) {
      int n = n0 + wn * 64 + j * 16 + l15;
      float bv = bias[n];
#pragma unroll
      for (int r = 0; r < 4; ++r) {
        int m = mbase + r;
        float val = (acc[i][j][r] + bv) * oscale;
        if (mode == 0) {
          int b = m >> 11, s = m & 2047, h = n >> 6, dh = n & 63;
          ((u16*)outraw)[((((size_t)b * 16 + h) * 2048 + s) << 6) + dh] = f2bf(val);
        } else if (mode == 1) {
          int b = m >> 11, s = m & 2047, h = n >> 6, dh = n & 63;
          ((u16*)outraw)[((((size_t)b * 16 + h) * 64 + dh) << 11) + s] = f2bf(val);
        } else {
          ((float*)outraw)[(size_t)m * 1024 + n] = val;
        }
      }
    }
  }
}

__global__ __launch_bounds__(256) void gemm_qkv_kernel(
    const u16* __restrict__ qb, const u16* __restrict__ kb, const u16* __restrict__ vb,
    const u16* __restrict__ Wqb, const float* __restrict__ bq,
    const u16* __restrict__ Wkb, const float* __restrict__ bk,
    const u16* __restrict__ Wvb, const float* __restrict__ bv,
    u16* __restrict__ qp, u16* __restrict__ kp, u16* __restrict__ vt) {
  if (blockIdx.z == 0)      gemm_body(qb, Wqb, bq, qp, 0, QSCALE);
  else if (blockIdx.z == 1) gemm_body(kb, Wkb, bk, kp, 0, 1.0f);
  else                      gemm_body(vb, Wvb, bv, vt, 1, 1.0f);
}

__global__ __launch_bounds__(256) void gemm_o_kernel(
    const u16* __restrict__ joint, const u16* __restrict__ Wob,
    const float* __restrict__ bo, float* __restrict__ out) {
  gemm_body(joint, Wob, bo, out, 2, 1.0f);
}

// ---------- flash attention, 32x32 MFMA, in-register P (T12) ----------
// Layout change attacking the measured LDS-pipe bottleneck (rounds 0-3):
//  * S^T = mfma32(K,Q): lane holds P^T[.][q=lane&31] spread only across the
//    lane<32/>=32 halves -> PV B-operand rebuilt IN-REGISTER with
//    v_cvt_pk_bf16_f32 + v_permlane32_swap_b32 (T12). The per-wave P^T LDS
//    roundtrip (16 writes + 4 reads + lgkmcnt drain per iter) is gone.
//  * K/V LDS tiles [row][64] with 16B-slot XOR swizzle slot^=(row&7):
//    staging pre-swizzles the GLOBAL source address (linear gload_lds dest),
//    fragment reads apply the same XOR -> bank-balanced (8 dwords/bank).
//  * 16 mfma32 per tile replace 32 mfma16 (same FLOPs, ~17% fewer matrix
//    pipe cycles).
// LDS ops per wave-iter: 28 -> 16. LDS/block: 48KB -> 32KB.
__global__ __launch_bounds__(256, 2) void attn_kernel(
    const u16* __restrict__ qp, const u16* __restrict__ kp,
    const u16* __restrict__ vt, const u64* __restrict__ pm,
    u16* __restrict__ joint) {
  alignas(16) __shared__ u16 kbuf[2][4096];   // [64 kv][8 slot16B] swizzled
  alignas(16) __shared__ u16 vbuf[2][4096];   // [64 dh][8 slot16B] swizzled

  const int tid = threadIdx.x, lane = tid & 63, wv = tid >> 6;
  const int l31 = lane & 31, hi = lane >> 5, l7 = lane & 7;
  const int q0 = blockIdx.x * 128;
  const int hd = blockIdx.y, b = blockIdx.z;
  const size_t head_off = ((size_t)b * 16 + hd) * 2048 * 64;
  const u16* Qh = qp + head_off;   // [2048][64]  (pre-scaled)
  const u16* Kh = kp + head_off;   // [2048][64]
  const u16* Vh = vt + head_off;   // [64][2048]  (dh-major)
  const int qr = q0 + wv * 32 + l31;                    // this lane's q row
  const u64* pmq = pm + ((size_t)b * 2048 + qr) * 32;

  // Q fragments: B-operand per dh-subtile d: lane holds Q[qr][d*16+hi*8+j]
  bf16x8 qf[4];
  {
    const u16* qrow = Qh + (size_t)qr * 64 + hi * 8;
#pragma unroll
    for (int d = 0; d < 4; ++d) qf[d] = *(const bf16x8*)(qrow + d * 16);
  }

  // staging: 512 slots of 16B per tile; slot sd -> row sd>>3, slot16 sd&7.
  // source column pre-swizzled: elem = ((sd&7) ^ ((sd>>3)&7)) * 8
  const int sd0 = tid, sd1 = 256 + tid;
  const int kr0 = sd0 >> 3, ks0 = ((sd0 & 7) ^ (kr0 & 7)) * 8;
  const int kr1 = sd1 >> 3, ks1 = ((sd1 & 7) ^ (kr1 & 7)) * 8;
  const u16* kg0 = Kh + (size_t)kr0 * 64 + ks0;
  const u16* kg1 = Kh + (size_t)kr1 * 64 + ks1;
  const u16* vg0 = Vh + (size_t)kr0 * 2048 + ks0;
  const u16* vg1 = Vh + (size_t)kr1 * 2048 + ks1;

  f32x16 O[2] = {};                // O^T: dh=g*32+(r&3)+8*(r>>2)+4*hi, q=l31
  f32x4 lacc = {};                 // 4-chain l partials
  const f32x16 fz16 = {};

  // prologue: stage tile 0
  async16(kg0, (char*)kbuf[0] + sd0 * 16);
  async16(kg1, (char*)kbuf[0] + sd1 * 16);
  async16(vg0, (char*)vbuf[0] + sd0 * 16);
  async16(vg1, (char*)vbuf[0] + sd1 * 16);

  for (int kt = 0; kt < 32; ++kt) {
    __syncthreads();

    // prefetch next tile
    if (kt != 31) {
      const size_t kadv = (size_t)(kt + 1) * 4096;   // 64 rows x 64 elems
      const int vadv = (kt + 1) * 64;                // +64 kv columns
      char* kd = (char*)kbuf[(kt + 1) & 1];
      char* vd = (char*)vbuf[(kt + 1) & 1];
      async16(kg0 + kadv, kd + sd0 * 16);
      async16(kg1 + kadv, kd + sd1 * 16);
      async16(vg0 + vadv, vd + sd0 * 16);
      async16(vg1 + vadv, vd + sd1 * 16);
    }

    u64 word = pmq[kt];
    const char* kc = (const char*)kbuf[kt & 1];
    const char* vc = (const char*)vbuf[kt & 1];

    // ---- K fragments: A-operand, lane = K[h*32+l31][d*16+hi*8+j] ----
    bf16x8 kf[2][4];
#pragma unroll
    for (int h = 0; h < 2; ++h)
#pragma unroll
      for (int d = 0; d < 4; ++d)
        kf[h][d] = *(const bf16x8*)(kc + (h * 32 + l31) * 128 +
                                    (((2 * d + hi) ^ l7) << 4));

    // ---- S^T = K.Q^T : two 32x32 outputs (kv halves), chained over dh ----
    f32x16 S[2];
#pragma unroll
    for (int h = 0; h < 2; ++h) {
      f32x16 s = mfma32(kf[h][0], qf[0], fz16);
      s = mfma32(kf[h][1], qf[1], s);
      s = mfma32(kf[h][2], qf[2], s);
      S[h] = mfma32(kf[h][3], qf[3], s);
    }

    // ---- V fragments: A-operand, lane = V^T[g*32+l31][ks*16+hi*8+j] ----
    bf16x8 vf[2][4];
#pragma unroll
    for (int g = 0; g < 2; ++g)
#pragma unroll
      for (int ks = 0; ks < 4; ++ks)
        vf[g][ks] = *(const bf16x8*)(vc + (g * 32 + l31) * 128 +
                                     (((2 * ks + hi) ^ l7) << 4));

    // ---- masked exp2 + l accumulation (kv = h*32 + (r&3)+8*(r>>2)+4*hi) --
    {
      const int hi4 = hi * 4;
#pragma unroll
      for (int h = 0; h < 2; ++h) {
        u32 wh = (h == 0) ? (u32)word : (u32)(word >> 32);
#pragma unroll
        for (int rq = 0; rq < 4; ++rq) {
          u32 nib = wh >> (rq * 8 + hi4);
#pragma unroll
          for (int r4 = 0; r4 < 4; ++r4) {
            int i = rq * 4 + r4;
            float pe = __builtin_amdgcn_exp2f(S[h][i]);
            S[h][i] = ((nib >> r4) & 1u) ? pe : 0.f;
          }
          f32x4 sv = {S[h][rq * 4 + 0], S[h][rq * 4 + 1],
                      S[h][rq * 4 + 2], S[h][rq * 4 + 3]};
          lacc += sv;
        }
      }
    }

    // ---- P^T -> PV B-operand, fully in-register (cvt_pk + permlane) ----
    // target lane needs P^T[ks*16 + hi*8 + j][q=l31]; source reg for elem j:
    // rq = (ks&1)*2 + hi_target, r4 = j&3, source half = j>>2.
    bf16x8 pf[4];
#pragma unroll
    for (int ks = 0; ks < 4; ++ks) {
      int h = ks >> 1;
      int ra = (ks & 1) * 8;        // rq_a*4
      u32 w0a = cvtpk(S[h][ra + 0], S[h][ra + 1]);
      u32 w1a = cvtpk(S[h][ra + 2], S[h][ra + 3]);
      u32 w0b = cvtpk(S[h][ra + 4], S[h][ra + 5]);
      u32 w1b = cvtpk(S[h][ra + 6], S[h][ra + 7]);
      pswap(w0a, w0b);   // w0a -> dword0 (all lanes), w0b -> dword2
      pswap(w1a, w1b);   // w1a -> dword1,              w1b -> dword3
      u32x4 t = {w0a, w1a, w0b, w1b};
      pf[ks] = __builtin_bit_cast(bf16x8, t);
    }

    // ---- O^T += V^T . P^T ----
#pragma unroll
    for (int g = 0; g < 2; ++g) {
      f32x16 o = O[g];
      o = mfma32(vf[g][0], pf[0], o);
      o = mfma32(vf[g][1], pf[1], o);
      o = mfma32(vf[g][2], pf[2], o);
      O[g] = mfma32(vf[g][3], pf[3], o);
    }
  }

  // ---- epilogue ----
  {
    float l = (lacc[0] + lacc[1]) + (lacc[2] + lacc[3]);
    l += __shfl_xor(l, 32, 64);    // lanes l / l+32 hold complementary kv
    float inv = 1.0f / l;
    size_t row_off = ((size_t)b * 2048 + qr) * 1024 + hd * 64;
#pragma unroll
    for (int g = 0; g < 2; ++g)
#pragma unroll
      for (int rq = 0; rq < 4; ++rq) {
        f32x4 ov = {O[g][rq * 4 + 0] * inv, O[g][rq * 4 + 1] * inv,
                    O[g][rq * 4 + 2] * inv, O[g][rq * 4 + 3] * inv};
        bf16x4 obv = __builtin_convertvector(ov, bf16x4);
        *(u64*)(joint + row_off + g * 32 + rq * 8 + hi * 4) =
            *(const u64*)&obv;
      }
  }
}

// ---------- launch ----------
extern "C" void kernel_launch(void* const* d_in, const int* in_sizes, int n_in,
                              void* d_out, int out_size, void* d_ws, size_t ws_size,
                              hipStream_t stream) {
  const float* q  = (const float*)d_in[0];
  const float* k  = (const float*)d_in[1];
  const float* v  = (const float*)d_in[2];
  const int* mask = (const int*)d_in[3];
  const float* Wq = (const float*)d_in[4];
  const float* bq = (const float*)d_in[5];
  const float* Wk = (const float*)d_in[6];
  const float* bk = (const float*)d_in[7];
  const float* Wv = (const float*)d_in[8];
  const float* bv = (const float*)d_in[9];
  const float* Wo = (const float*)d_in[10];
  const float* bo = (const float*)d_in[11];
  float* out = (float*)d_out;

  u16* w = (u16*)d_ws;
  u16* qp    = w;                         // (B,H,S,Dh)
  u16* kp    = w + 4194304;               // (B,H,S,Dh)
  u16* vt    = w + 8388608;               // (B,H,Dh,S)
  u16* qb    = w + 12582912;              // bf16 q; joint aliases after attn
  u16* kb    = w + 16777216;
  u16* vb    = w + 20971520;
  u16* Wqb   = w + 25165824;
  u16* Wkb   = w + 26214400;
  u16* Wvb   = w + 27262976;
  u16* Wob   = w + 28311552;
  u64* pm    = (u64*)(w + 29360128);
  u16* joint = qb;

  CvtArgs ca;
  ca.src[0] = q;  ca.dst[0] = qb;
  ca.src[1] = k;  ca.dst[1] = kb;
  ca.src[2] = v;  ca.dst[2] = vb;
  ca.src[3] = Wq; ca.dst[3] = Wqb;
  ca.src[4] = Wk; ca.dst[4] = Wkb;
  ca.src[5] = Wv; ca.dst[5] = Wvb;
  ca.src[6] = Wo; ca.dst[6] = Wob;

  pack_mask_kernel<<<dim3(512), dim3(256), 0, stream>>>(mask, pm);
  cvt_kernel<<<dim3(2048, 1, 7), dim3(256), 0, stream>>>(ca);
  gemm_qkv_kernel<<<dim3(8, 32, 3), dim3(256), 0, stream>>>(
      qb, kb, vb, Wqb, bq, Wkb, bk, Wvb, bv, qp, kp, vt);
  attn_kernel<<<dim3(16, 16, 2), dim3(256), 0, stream>>>(qp, kp, vt, pm, joint);
  gemm_o_kernel<<<dim3(8, 32, 1), dim3(256), 0, stream>>>(joint, Wob, bo, out);
}

// Round 6
// 272.179 us; speedup vs baseline: 1.2810x; 1.0511x over previous
//
#include <hip/hip_runtime.h>

typedef unsigned short u16;
typedef unsigned int u32;
typedef unsigned long long u64;
typedef float f32x4 __attribute__((ext_vector_type(4)));
typedef float f32x16 __attribute__((ext_vector_type(16)));
typedef __bf16 bf16x4 __attribute__((ext_vector_type(4)));
typedef __bf16 bf16x8 __attribute__((ext_vector_type(8)));
typedef u16 u16x8 __attribute__((ext_vector_type(8)));
typedef u32 u32x4 __attribute__((ext_vector_type(4)));

#define QSCALE 0.18033688011112042f   /* 0.125 * log2(e) */

// ---------- helpers ----------
__device__ __forceinline__ u16 f2bf(float f) {
  unsigned int u = __float_as_uint(f);
  u += 0x7fffu + ((u >> 16) & 1u);   // round-to-nearest-even
  return (u16)(u >> 16);
}

// async global->LDS, 16B per lane; HW dest = readfirstlane(l) + lane*16.
__device__ __forceinline__ void async16(const void* g, void* l) {
  __builtin_amdgcn_global_load_lds(
      (__attribute__((address_space(1))) void*)g,
      (__attribute__((address_space(3))) void*)l,
      16, 0, 0);
}

__device__ __forceinline__ f32x4 mfma16(bf16x8 a, bf16x8 b, f32x4 c) {
  return __builtin_amdgcn_mfma_f32_16x16x32_bf16(a, b, c, 0, 0, 0);
}

__device__ __forceinline__ f32x16 mfma32(bf16x8 a, bf16x8 b, f32x16 c) {
  return __builtin_amdgcn_mfma_f32_32x32x16_bf16(a, b, c, 0, 0, 0);
}

// pack two f32 -> dword of 2 bf16 (RNE)
__device__ __forceinline__ u32 cvtpk(float lo, float hi) {
  u32 r;
  asm("v_cvt_pk_bf16_f32 %0, %1, %2" : "=v"(r) : "v"(lo), "v"(hi));
  return r;
}

// a' = {a.lo32lanes, b.lo32lanes}; b' = {a.hi32lanes, b.hi32lanes}
__device__ __forceinline__ void pswap(u32& a, u32& b) {
  asm("v_permlane32_swap_b32 %0, %1" : "+v"(a), "+v"(b));
}

// ---------- f32 -> bf16 bulk convert (7 tensors) ----------
struct CvtArgs {
  const float* src[7];
  u16* dst[7];
};

__global__ __launch_bounds__(256) void cvt_kernel(CvtArgs a) {
  int z = blockIdx.z;
  int n = (z < 3) ? 4194304 : 1048576;
  int base = (blockIdx.x * 256 + threadIdx.x) * 8;
  if (base >= n) return;
  const float* s = a.src[z] + base;
  f32x4 x0 = *(const f32x4*)s;
  f32x4 x1 = *(const f32x4*)(s + 4);
  u16x8 pk;
  pk[0]=f2bf(x0[0]); pk[1]=f2bf(x0[1]); pk[2]=f2bf(x0[2]); pk[3]=f2bf(x0[3]);
  pk[4]=f2bf(x1[0]); pk[5]=f2bf(x1[1]); pk[6]=f2bf(x1[2]); pk[7]=f2bf(x1[3]);
  *(u16x8*)(a.dst[z] + base) = pk;
}

// ---------- mask packing: (B,1,S,S) int32 -> (B,S,S/64) uint64 ----------
__global__ __launch_bounds__(256) void pack_mask_kernel(
    const int* __restrict__ mask, u64* __restrict__ pm) {
  int idx = blockIdx.x * 256 + threadIdx.x;
  const int4* src = (const int4*)(mask + (size_t)idx * 64);
  u64 bits = 0ull;
#pragma unroll
  for (int j = 0; j < 16; ++j) {
    int4 v = src[j];
    if (v.x) bits |= 1ull << (4 * j + 0);
    if (v.y) bits |= 1ull << (4 * j + 1);
    if (v.z) bits |= 1ull << (4 * j + 2);
    if (v.w) bits |= 1ull << (4 * j + 3);
  }
  pm[idx] = bits;
}

// ---------- GEMM (m97 structure) ----------
// mode 0: out (B,H,S,Dh)  mode 1: out (B,H,Dh,S)  mode 2: MxN f32
__device__ __forceinline__ void gemm_body(const u16* __restrict__ A,
                                          const u16* __restrict__ W,
                                          const float* __restrict__ bias,
                                          void* __restrict__ outraw, int mode,
                                          float oscale) {
  alignas(16) __shared__ u16 lA[128 * 32];
  alignas(16) __shared__ u16 lB[128 * 32];
  const int tid = threadIdx.x;
  const int lane = tid & 63, wv = tid >> 6;
  const int wm = wv >> 1, wn = wv & 1;
  const int m0 = blockIdx.y * 128, n0 = blockIdx.x * 128;
  const int l15 = lane & 15, quad = lane >> 4;
  const int srow = lane >> 2;
  const int scol = (lane & 3) * 8;

  f32x4 acc[4][4] = {};

  for (int k0 = 0; k0 < 1024; k0 += 32) {
#pragma unroll
    for (int t = 0; t < 2; ++t) {
      int rb = (wv * 2 + t) * 16;
      async16(A + (size_t)(m0 + rb + srow) * 1024 + k0 + scol, (char*)lA + rb * 64);
      async16(W + (size_t)(n0 + rb + srow) * 1024 + k0 + scol, (char*)lB + rb * 64);
    }
    __syncthreads();
    bf16x8 af[4], bfr[4];
#pragma unroll
    for (int i = 0; i < 4; ++i) {
      af[i]  = *(const bf16x8*)(lA + (wm * 64 + i * 16 + l15) * 32 + quad * 8);
      bfr[i] = *(const bf16x8*)(lB + (wn * 64 + i * 16 + l15) * 32 + quad * 8);
    }
#pragma unroll
    for (int i = 0; i < 4; ++i)
#pragma unroll
      for (int j = 0; j < 4; ++j)
        acc[i][j] = mfma16(af[i], bfr[j], acc[i][j]);
    __syncthreads();
  }

#pragma unroll
  for (int i = 0; i < 4; ++i) {
    int mbase = m0 + wm * 64 + i * 16 + quad * 4;
#pragma unroll
    for (int j = 0; j < 4; ++j) {
      int n = n0 + wn * 64 + j * 16 + l15;
      float bv = bias[n];
#pragma unroll
      for (int r = 0; r < 4; ++r) {
        int m = mbase + r;
        float val = (acc[i][j][r] + bv) * oscale;
        if (mode == 0) {
          int b = m >> 11, s = m & 2047, h = n >> 6, dh = n & 63;
          ((u16*)outraw)[((((size_t)b * 16 + h) * 2048 + s) << 6) + dh] = f2bf(val);
        } else if (mode == 1) {
          int b = m >> 11, s = m & 2047, h = n >> 6, dh = n & 63;
          ((u16*)outraw)[((((size_t)b * 16 + h) * 64 + dh) << 11) + s] = f2bf(val);
        } else {
          ((float*)outraw)[(size_t)m * 1024 + n] = val;
        }
      }
    }
  }
}

__global__ __launch_bounds__(256) void gemm_qkv_kernel(
    const u16* __restrict__ qb, const u16* __restrict__ kb, const u16* __restrict__ vb,
    const u16* __restrict__ Wqb, const float* __restrict__ bq,
    const u16* __restrict__ Wkb, const float* __restrict__ bk,
    const u16* __restrict__ Wvb, const float* __restrict__ bv,
    u16* __restrict__ qp, u16* __restrict__ kp, u16* __restrict__ vt) {
  if (blockIdx.z == 0)      gemm_body(qb, Wqb, bq, qp, 0, QSCALE);
  else if (blockIdx.z == 1) gemm_body(kb, Wkb, bk, kp, 0, 1.0f);
  else                      gemm_body(vb, Wvb, bv, vt, 1, 1.0f);
}

__global__ __launch_bounds__(256) void gemm_o_kernel(
    const u16* __restrict__ joint, const u16* __restrict__ Wob,
    const float* __restrict__ bo, float* __restrict__ out) {
  gemm_body(joint, Wob, bo, out, 2, 1.0f);
}

// ---------- flash attention, 32x32 MFMA, in-reg P, KV-split waves ----------
// vs round-4 (71 us): two changes attacking the measured stall pattern
// (per-iter wall ~5.4K cyc vs ~1.1K issue work at 2 waves/SIMD):
//  1. KV-SPLIT: waves (qg,kh) pair on one 32-q-row group; wave kh handles kv
//     half kh*32..+31 of every tile. ALL per-wave per-iter work halves
//     (4 kf + 4 vf reads, 8 mfma32, 16 exp2, 8 cvtpk) -> grid 1024 blocks,
//     4 independent blocks/CU, 4 waves/SIMD; per-CU LDS work only +20%
//     (extra staging), unlike the failed R3 q-split (+90%). One cross-wave
//     O/l reduction at the end via smem reuse (aliased, once).
//  2. XCD-BIJECTIVE SWIZZLE (T1): all 32 blocks of one (b,h) land on one
//     XCD -> that head's 512KB K/V stays in one L2 (2MB/XCD working set).
//     Attacks FETCH_SIZE 70MB vs ~34MB minimal.
__global__ __launch_bounds__(256, 4) void attn_kernel(
    const u16* __restrict__ qp, const u16* __restrict__ kp,
    const u16* __restrict__ vt, const u64* __restrict__ pm,
    u16* __restrict__ joint) {
  // smem: [0,8K) kbuf0 | [8K,16K) kbuf1 | [16K,24K) vbuf0 | [24K,32K) vbuf1
  // reused after the K-loop as float exch[2][64][34] (17.4 KB)
  alignas(16) __shared__ char smem[32768];

  const int tid = threadIdx.x, lane = tid & 63, wv = tid >> 6;
  const int l31 = lane & 31, hi = lane >> 5, l7 = lane & 7;
  const int qg = wv >> 1, kh = wv & 1;    // q-group, kv-half of this wave

  // XCD-bijective decode: blocks with equal grp share (b,h) AND xcd=bid&7
  const int linear = blockIdx.x;
  const int xcd = linear & 7, slot = linear >> 3;
  const int grp = (xcd << 2) | (slot >> 5);   // 0..31 = (b,h)
  const int q0 = (slot & 31) * 64;
  const int hd = grp & 15, b = grp >> 4;

  const size_t head_off = ((size_t)b * 16 + hd) * 2048 * 64;
  const u16* Qh = qp + head_off;   // [2048][64]  (pre-scaled)
  const u16* Kh = kp + head_off;   // [2048][64]
  const u16* Vh = vt + head_off;   // [64][2048]  (dh-major)
  const int qr = q0 + qg * 32 + l31;                    // this lane's q row
  const u32* pmq32 = (const u32*)(pm + ((size_t)b * 2048 + qr) * 32) + kh;

  // Q fragments: B-operand per dh-subtile d: lane holds Q[qr][d*16+hi*8+j]
  bf16x8 qf[4];
  {
    const u16* qrow = Qh + (size_t)qr * 64 + hi * 8;
#pragma unroll
    for (int d = 0; d < 4; ++d) qf[d] = *(const bf16x8*)(qrow + d * 16);
  }

  // staging: 512 slots of 16B per tile; slot sd -> row sd>>3, slot16 sd&7.
  // source column pre-swizzled: elem = ((sd&7) ^ ((sd>>3)&7)) * 8
  const int sd0 = tid, sd1 = 256 + tid;
  const int kr0 = sd0 >> 3, ks0 = ((sd0 & 7) ^ (kr0 & 7)) * 8;
  const int kr1 = sd1 >> 3, ks1 = ((sd1 & 7) ^ (kr1 & 7)) * 8;
  const u16* kg0 = Kh + (size_t)kr0 * 64 + ks0;
  const u16* kg1 = Kh + (size_t)kr1 * 64 + ks1;
  const u16* vg0 = Vh + (size_t)kr0 * 2048 + ks0;
  const u16* vg1 = Vh + (size_t)kr1 * 2048 + ks1;

  f32x16 O[2] = {};                // O^T: dh=g*32+(r&3)+8*(r>>2)+4*hi, q=l31
  f32x4 lacc = {};                 // 4-chain l partials (kv-half only)
  const f32x16 fz16 = {};

  // prologue: stage tile 0
  async16(kg0, smem + sd0 * 16);
  async16(kg1, smem + sd1 * 16);
  async16(vg0, smem + 16384 + sd0 * 16);
  async16(vg1, smem + 16384 + sd1 * 16);

  for (int kt = 0; kt < 32; ++kt) {
    __syncthreads();

    // prefetch next tile
    if (kt != 31) {
      const size_t kadv = (size_t)(kt + 1) * 4096;   // 64 rows x 64 elems
      const int vadv = (kt + 1) * 64;                // +64 kv columns
      char* kd = smem + (((kt + 1) & 1) << 13);
      char* vd = smem + 16384 + (((kt + 1) & 1) << 13);
      async16(kg0 + kadv, kd + sd0 * 16);
      async16(kg1 + kadv, kd + sd1 * 16);
      async16(vg0 + vadv, vd + sd0 * 16);
      async16(vg1 + vadv, vd + sd1 * 16);
    }

    u32 wh = pmq32[2 * kt];        // mask bits for this wave's kv half
    const char* kc = smem + ((kt & 1) << 13);
    const char* vc = smem + 16384 + ((kt & 1) << 13);

    // ---- K fragments: A-operand, lane = K[kh*32+l31][d*16+hi*8+j] ----
    bf16x8 kf[4];
#pragma unroll
    for (int d = 0; d < 4; ++d)
      kf[d] = *(const bf16x8*)(kc + (kh * 32 + l31) * 128 +
                               (((2 * d + hi) ^ l7) << 4));

    // ---- S^T (this wave's 32x32 kv-half), chained over dh ----
    f32x16 S;
    {
      f32x16 s = mfma32(kf[0], qf[0], fz16);
      s = mfma32(kf[1], qf[1], s);
      s = mfma32(kf[2], qf[2], s);
      S = mfma32(kf[3], qf[3], s);
    }

    // ---- V fragments: A-operand, lane = V^T[g*32+l31][ks*16+hi*8+j],
    //      ks = kh*2 + t  (this wave's kv-half slices) ----
    bf16x8 vf[2][2];
#pragma unroll
    for (int g = 0; g < 2; ++g)
#pragma unroll
      for (int t = 0; t < 2; ++t) {
        int ks = kh * 2 + t;
        vf[g][t] = *(const bf16x8*)(vc + (g * 32 + l31) * 128 +
                                    (((2 * ks + hi) ^ l7) << 4));
      }

    // ---- masked exp2 + l accumulation (kv' = (r&3)+8*(r>>2)+4*hi) ----
    {
      const int hi4 = hi * 4;
#pragma unroll
      for (int rq = 0; rq < 4; ++rq) {
        u32 nib = wh >> (rq * 8 + hi4);
#pragma unroll
        for (int r4 = 0; r4 < 4; ++r4) {
          int i = rq * 4 + r4;
          float pe = __builtin_amdgcn_exp2f(S[i]);
          S[i] = ((nib >> r4) & 1u) ? pe : 0.f;
        }
        f32x4 sv = {S[rq * 4 + 0], S[rq * 4 + 1], S[rq * 4 + 2], S[rq * 4 + 3]};
        lacc += sv;
      }
    }

    // ---- P^T -> PV B-operand, in-register (cvt_pk + permlane, T12) ----
    bf16x8 pf[2];
#pragma unroll
    for (int t = 0; t < 2; ++t) {
      int ra = t * 8;
      u32 w0a = cvtpk(S[ra + 0], S[ra + 1]);
      u32 w1a = cvtpk(S[ra + 2], S[ra + 3]);
      u32 w0b = cvtpk(S[ra + 4], S[ra + 5]);
      u32 w1b = cvtpk(S[ra + 6], S[ra + 7]);
      pswap(w0a, w0b);   // dword0 / dword2
      pswap(w1a, w1b);   // dword1 / dword3
      u32x4 tt = {w0a, w1a, w0b, w1b};
      pf[t] = __builtin_bit_cast(bf16x8, tt);
    }

    // ---- O^T += V^T . P^T (this kv-half's contribution) ----
#pragma unroll
    for (int g = 0; g < 2; ++g) {
      f32x16 o = O[g];
      o = mfma32(vf[g][0], pf[0], o);
      O[g] = mfma32(vf[g][1], pf[1], o);
    }
  }

  // ---- epilogue: cross-wave (kv-half) reduction, then normalize+store ----
  float lp = (lacc[0] + lacc[1]) + (lacc[2] + lacc[3]);
  lp += __shfl_xor(lp, 32, 64);    // hi/lo lanes hold complementary kv rows
  __syncthreads();                 // all K/V tile reads done; smem reusable
  float* exch = (float*)smem;      // [2][64][34] floats, 17.4 KB
  if (kh == 1) {
    float* e = exch + (qg * 64 + lane) * 34;
#pragma unroll
    for (int g = 0; g < 2; ++g)
#pragma unroll
      for (int i = 0; i < 16; ++i) e[g * 16 + i] = O[g][i];
    e[32] = lp;
  }
  __syncthreads();
  if (kh == 0) {
    const float* e = exch + (qg * 64 + lane) * 34;
#pragma unroll
    for (int g = 0; g < 2; ++g)
#pragma unroll
      for (int i = 0; i < 16; ++i) O[g][i] += e[g * 16 + i];
    lp += e[32];
    float inv = 1.0f / lp;
    size_t row_off = ((size_t)b * 2048 + qr) * 1024 + hd * 64;
#pragma unroll
    for (int g = 0; g < 2; ++g)
#pragma unroll
      for (int rq = 0; rq < 4; ++rq) {
        f32x4 ov = {O[g][rq * 4 + 0] * inv, O[g][rq * 4 + 1] * inv,
                    O[g][rq * 4 + 2] * inv, O[g][rq * 4 + 3] * inv};
        bf16x4 obv = __builtin_convertvector(ov, bf16x4);
        *(u64*)(joint + row_off + g * 32 + rq * 8 + hi * 4) =
            *(const u64*)&obv;
      }
  }
}

// ---------- launch ----------
extern "C" void kernel_launch(void* const* d_in, const int* in_sizes, int n_in,
                              void* d_out, int out_size, void* d_ws, size_t ws_size,
                              hipStream_t stream) {
  const float* q  = (const float*)d_in[0];
  const float* k  = (const float*)d_in[1];
  const float* v  = (const float*)d_in[2];
  const int* mask = (const int*)d_in[3];
  const float* Wq = (const float*)d_in[4];
  const float* bq = (const float*)d_in[5];
  const float* Wk = (const float*)d_in[6];
  const float* bk = (const float*)d_in[7];
  const float* Wv = (const float*)d_in[8];
  const float* bv = (const float*)d_in[9];
  const float* Wo = (const float*)d_in[10];
  const float* bo = (const float*)d_in[11];
  float* out = (float*)d_out;

  u16* w = (u16*)d_ws;
  u16* qp    = w;                         // (B,H,S,Dh)
  u16* kp    = w + 4194304;               // (B,H,S,Dh)
  u16* vt    = w + 8388608;               // (B,H,Dh,S)
  u16* qb    = w + 12582912;              // bf16 q; joint aliases after attn
  u16* kb    = w + 16777216;
  u16* vb    = w + 20971520;
  u16* Wqb   = w + 25165824;
  u16* Wkb   = w + 26214400;
  u16* Wvb   = w + 27262976;
  u16* Wob   = w + 28311552;
  u64* pm    = (u64*)(w + 29360128);
  u16* joint = qb;

  CvtArgs ca;
  ca.src[0] = q;  ca.dst[0] = qb;
  ca.src[1] = k;  ca.dst[1] = kb;
  ca.src[2] = v;  ca.dst[2] = vb;
  ca.src[3] = Wq; ca.dst[3] = Wqb;
  ca.src[4] = Wk; ca.dst[4] = Wkb;
  ca.src[5] = Wv; ca.dst[5] = Wvb;
  ca.src[6] = Wo; ca.dst[6] = Wob;

  pack_mask_kernel<<<dim3(512), dim3(256), 0, stream>>>(mask, pm);
  cvt_kernel<<<dim3(2048, 1, 7), dim3(256), 0, stream>>>(ca);
  gemm_qkv_kernel<<<dim3(8, 32, 3), dim3(256), 0, stream>>>(
      qb, kb, vb, Wqb, bq, Wkb, bk, Wvb, bv, qp, kp, vt);
  attn_kernel<<<dim3(1024), dim3(256), 0, stream>>>(qp, kp, vt, pm, joint);
  gemm_o_kernel<<<dim3(8, 32, 1), dim3(256), 0, stream>>>(joint, Wob, bo, out);
}